// Round 8
// baseline (187.653 us; speedup 1.0000x reference)
//
#include <hip/hip_runtime.h>
#include <hip/hip_bf16.h>
#include <stdint.h>

#define NB 256
#define LQ 128
#define LC 512
#define DIM 384

typedef __attribute__((ext_vector_type(8))) short short8;
typedef __attribute__((ext_vector_type(4))) float f4;
typedef __attribute__((ext_vector_type(2))) unsigned int u32x2;

__device__ __forceinline__ unsigned int pk2bf(float a, float b) {
  union { float f; uint32_t u; } x, y; x.f = a; y.f = b;
  uint32_t lo = (x.u + 0x7fffu + ((x.u >> 16) & 1u)) >> 16;
  uint32_t hi = (y.u + 0x7fffu + ((y.u >> 16) & 1u)) >> 16;
  return lo | (hi << 16);
}

__device__ __forceinline__ void gload16(const void* g, void* l) {
  __builtin_amdgcn_global_load_lds(
      (const __attribute__((address_space(1))) void*)g,
      (__attribute__((address_space(3))) void*)l, 16, 0, 0);
}

__device__ __forceinline__ void barrier_pinned() {
  __builtin_amdgcn_sched_barrier(0);
  __builtin_amdgcn_s_barrier();
  __builtin_amdgcn_sched_barrier(0);
}

// ============================== K1: convert + pool ===========================
// Round-8: pure streaming. f4 loads (16B/lane), RAW bf16 stores (8B/lane) that
// do NOT depend on the row reduce; 1/||row|| goes to qinv/cinv side arrays
// (normalization applied in maxsim's max-fold). 8-row batches for load ILP.
// Full-row chunks: v[i] = row i, f4 chunk `lane` (cols 0..255).
// Tail chunks: vh[j] = row 2j (lanes<32) / 2j+1 (lanes>=32), chunk 64+(lane&31).
template <int N>
__device__ __forceinline__ void batch_rows(const float* __restrict__ src0,
                                           const int* __restrict__ mask0,
                                           unsigned short* __restrict__ dst0,
                                           float* __restrict__ invout,
                                           int lane, f4& accA, f4& accB, float& cnt) {
  const bool hiHalf = lane >= 32;
  const int l31 = lane & 31;
  f4 v[N], vh[N / 2];
#pragma unroll
  for (int i = 0; i < N; ++i)
    v[i] = *((const f4*)(src0 + (size_t)i * DIM) + lane);
#pragma unroll
  for (int j = 0; j < N / 2; ++j)
    vh[j] = *((const f4*)(src0 + (size_t)(2 * j + (hiHalf ? 1 : 0)) * DIM) + 64 + l31);

  // raw bf16 stores — independent of the reduction chain
#pragma unroll
  for (int i = 0; i < N; ++i) {
    u32x2 w; w[0] = pk2bf(v[i].x, v[i].y); w[1] = pk2bf(v[i].z, v[i].w);
    *(u32x2*)(dst0 + (size_t)i * DIM + 4 * lane) = w;
  }
#pragma unroll
  for (int j = 0; j < N / 2; ++j) {
    u32x2 w; w[0] = pk2bf(vh[j].x, vh[j].y); w[1] = pk2bf(vh[j].z, vh[j].w);
    *(u32x2*)(dst0 + (size_t)(2 * j + (hiHalf ? 1 : 0)) * DIM + 256 + 4 * l31) = w;
  }

  // interleaved sumsq reduce (off the store path)
  float ss[N];
#pragma unroll
  for (int i = 0; i < N; ++i)
    ss[i] = v[i].x * v[i].x + v[i].y * v[i].y + v[i].z * v[i].z + v[i].w * v[i].w;
#pragma unroll
  for (int j = 0; j < N / 2; ++j) {
    const float td = vh[j].x * vh[j].x + vh[j].y * vh[j].y
                   + vh[j].z * vh[j].z + vh[j].w * vh[j].w;
    if (hiHalf) ss[2 * j + 1] += td; else ss[2 * j] += td;  // static reg indices
  }
#pragma unroll
  for (int o = 32; o; o >>= 1) {
#pragma unroll
    for (int i = 0; i < N; ++i) ss[i] += __shfl_xor(ss[i], o);
  }

  // masked pooled partials
  float fm[N];
#pragma unroll
  for (int i = 0; i < N; ++i) fm[i] = (float)mask0[i];
#pragma unroll
  for (int i = 0; i < N; ++i) { accA += v[i] * fm[i]; cnt += fm[i]; }
#pragma unroll
  for (int j = 0; j < N / 2; ++j) {
    const float fmt = hiHalf ? fm[2 * j + 1] : fm[2 * j];
    accB += vh[j] * fmt;
  }
  if (lane == 0) {
#pragma unroll
    for (int i = 0; i < N; ++i)
      invout[i] = 1.0f / fmaxf(sqrtf(ss[i]), 1e-12f);
  }
}

__global__ __launch_bounds__(256, 4)
void normalize_pool(const float* __restrict__ qtok, const float* __restrict__ ctok,
                    const int* __restrict__ qm, const int* __restrict__ cm,
                    unsigned short* __restrict__ qn, unsigned short* __restrict__ cn,
                    float* __restrict__ qinv, float* __restrict__ cinv,
                    float* __restrict__ pp, float* __restrict__ nn) {
  __shared__ float s_redA[4][2][256];
  __shared__ float s_redB[4][2][2][128];
  __shared__ float s_cnt[4][2];
  const int bid = blockIdx.x;
  const int b = bid >> 3, s = bid & 7;
  const int tid = threadIdx.x, wave = tid >> 6, lane = tid & 63;
  const bool hiHalf = lane >= 32;
  const int l31 = lane & 31;

  f4 aqA = {0,0,0,0}, aqB = {0,0,0,0}, acA = {0,0,0,0}, acB = {0,0,0,0};
  float cq = 0.f, cc = 0.f;

  {  // 4 q rows
    const int r0 = b * LQ + s * 16 + wave * 4;
    batch_rows<4>(qtok + (size_t)r0 * DIM, qm + r0, qn + (size_t)r0 * DIM,
                  qinv + r0, lane, aqA, aqB, cq);
  }
  {  // 16 c rows, two batches of 8
    const int r0 = b * LC + s * 64 + wave * 16;
    batch_rows<8>(ctok + (size_t)r0 * DIM, cm + r0, cn + (size_t)r0 * DIM,
                  cinv + r0, lane, acA, acB, cc);
    batch_rows<8>(ctok + (size_t)(r0 + 8) * DIM, cm + r0 + 8,
                  cn + (size_t)(r0 + 8) * DIM, cinv + r0 + 8, lane, acA, acB, cc);
  }

  *(f4*)&s_redA[wave][0][4 * lane] = aqA;
  *(f4*)&s_redA[wave][1][4 * lane] = acA;
  *(f4*)&s_redB[wave][0][hiHalf ? 1 : 0][4 * l31] = aqB;
  *(f4*)&s_redB[wave][1][hiHalf ? 1 : 0][4 * l31] = acB;
  if (lane == 0) { s_cnt[wave][0] = cq; s_cnt[wave][1] = cc; }
  __syncthreads();

  for (int d = tid; d < DIM; d += 256) {
    float sq = 0.f, sc = 0.f;
    if (d < 256) {
#pragma unroll
      for (int w = 0; w < 4; ++w) { sq += s_redA[w][0][d]; sc += s_redA[w][1][d]; }
    } else {
#pragma unroll
      for (int w = 0; w < 4; ++w) {
        sq += s_redB[w][0][0][d - 256] + s_redB[w][0][1][d - 256];
        sc += s_redB[w][1][0][d - 256] + s_redB[w][1][1][d - 256];
      }
    }
    pp[(size_t)bid * 768 + d] = sq;
    pp[(size_t)bid * 768 + DIM + d] = sc;
  }
  if (tid == 0) {
    nn[bid * 2]     = s_cnt[0][0] + s_cnt[1][0] + s_cnt[2][0] + s_cnt[3][0];
    nn[bid * 2 + 1] = s_cnt[0][1] + s_cnt[1][1] + s_cnt[2][1] + s_cnt[3][1];
  }
}

// ============================== K2: maxsim (MFMA) ============================
// grid 512: (b = bid>>1, c-half s = bid&1). 8 waves. Raw-bf16 q A-frags in
// registers; raw-bf16 c staged via global_load_lds 3-buffer ring (swizzled),
// counted vmcnt(3). Normalization applied as acc * (qi*ci) before mask/max.
__global__ __launch_bounds__(512, 4)
void maxsim(const unsigned short* __restrict__ qn, const unsigned short* __restrict__ cn,
            const int* __restrict__ cm, const float* __restrict__ qinv,
            const float* __restrict__ cinv, float* __restrict__ ws_rm) {
  __shared__ __attribute__((aligned(128))) char ring[3][24576];
  __shared__ int s_cm[256];
  __shared__ float s_ci[256];
  __shared__ float s_qi[LQ];
  const int bid = blockIdx.x;
  const int b = bid >> 1, s = bid & 1;
  const int tid = threadIdx.x, wave = tid >> 6, lane = tid & 63;
  const int rA = lane & 15, hi = lane >> 4;

  if (tid < 256) {
    s_cm[tid] = cm[b * LC + s * 256 + tid];
    s_ci[tid] = cinv[b * LC + s * 256 + tid];
  } else if (tid < 256 + LQ) {
    s_qi[tid - 256] = qinv[b * LQ + (tid - 256)];
  }
  __syncthreads();

  const char* qbase = (const char*)(qn + (size_t)b * LQ * DIM);
  const char* cbase = (const char*)(cn + (size_t)b * LC * DIM) + (size_t)s * 256 * 768;

  // per-lane swizzled DMA source offsets for one 32x768B tile (3 issues/lane):
  // LDS chunk n=(row,col) holds global chunk (row, col^(row&7)).
  int goff[3];
#pragma unroll
  for (int j = 0; j < 3; ++j) {
    const unsigned n = (unsigned)j * 512u + (unsigned)wave * 64u + (unsigned)lane;
    const unsigned row = n / 48u, col = n % 48u;
    goff[j] = (int)(row * 768u + ((col ^ (row & 7u)) << 4));
  }

  // ---- q prologue round A: tiles 0..2 -> bufs 0..2
#pragma unroll
  for (int tile = 0; tile < 3; ++tile) {
    char* dst = ring[tile] + wave * 1024;
#pragma unroll
    for (int j = 0; j < 3; ++j) gload16(qbase + tile * 24576 + goff[j], dst + j * 8192);
  }
  asm volatile("s_waitcnt vmcnt(0)" ::: "memory");
  barrier_pinned();

  short8 A[12] = {};
  if (wave < 6) {
    const char* bp = ring[wave >> 1];
    const int lr = (wave & 1) * 16 + rA;
#pragma unroll
    for (int kk = 0; kk < 12; ++kk)
      A[kk] = *(const short8*)(bp + lr * 768 + (((kk * 4 + hi) ^ (lr & 7)) << 4));
    asm volatile("s_waitcnt lgkmcnt(0)" ::: "memory");
  }
  barrier_pinned();

  // ---- round B: tile 3 -> buf 0 (waves 6,7 read their frags)
  {
    char* dst = ring[0] + wave * 1024;
#pragma unroll
    for (int j = 0; j < 3; ++j) gload16(qbase + 3 * 24576 + goff[j], dst + j * 8192);
  }
  asm volatile("s_waitcnt vmcnt(0)" ::: "memory");
  barrier_pinned();
  if (wave >= 6) {
    const char* bp = ring[0];
    const int lr = (wave - 6) * 16 + rA;
#pragma unroll
    for (int kk = 0; kk < 12; ++kk)
      A[kk] = *(const short8*)(bp + lr * 768 + (((kk * 4 + hi) ^ (lr & 7)) << 4));
    asm volatile("s_waitcnt lgkmcnt(0)" ::: "memory");
  }
  barrier_pinned();

  // ---- issue c0 -> buf1, c1 -> buf2
#pragma unroll
  for (int t0 = 0; t0 < 2; ++t0) {
    char* dst = ring[t0 + 1] + wave * 1024;
#pragma unroll
    for (int j = 0; j < 3; ++j) gload16(cbase + (size_t)t0 * 24576 + goff[j], dst + j * 8192);
  }

  float rm[4] = {-1e9f, -1e9f, -1e9f, -1e9f};

  // ---- 8 c stages; stage t reads buf[(t+1)%3], issues c(t+2) -> buf[(t+3)%3]
#pragma unroll
  for (int t = 0; t < 8; ++t) {
    if (t == 7) { asm volatile("s_waitcnt vmcnt(0)" ::: "memory"); }
    else        { asm volatile("s_waitcnt vmcnt(3)" ::: "memory"); }
    barrier_pinned();

    const char* bp = ring[(t + 1) % 3];
    f4 acc0 = {0,0,0,0}, acc1 = {0,0,0,0};
#pragma unroll
    for (int kk = 0; kk < 12; ++kk) {
      const int sw = ((kk * 4 + hi) ^ (rA & 7)) << 4;
      const short8 b0 = *(const short8*)(bp + rA * 768 + sw);
      const short8 b1 = *(const short8*)(bp + (rA + 16) * 768 + sw);
      acc0 = __builtin_amdgcn_mfma_f32_16x16x32_bf16(A[kk], b0, acc0, 0, 0, 0);
      acc1 = __builtin_amdgcn_mfma_f32_16x16x32_bf16(A[kk], b1, acc1, 0, 0, 0);
    }
    if (t + 2 < 8) {
      char* dst = ring[(t + 3) % 3] + wave * 1024;
#pragma unroll
      for (int j = 0; j < 3; ++j) gload16(cbase + (size_t)(t + 2) * 24576 + goff[j], dst + j * 8192);
    }
    const bool v0 = s_cm[t * 32 + rA] != 0;
    const bool v1 = s_cm[t * 32 + rA + 16] != 0;
    const float ci0 = s_ci[t * 32 + rA];
    const float ci1 = s_ci[t * 32 + rA + 16];
#pragma unroll
    for (int r = 0; r < 4; ++r) {
      const float qi = s_qi[wave * 16 + hi * 4 + r];
      const float a0 = v0 ? acc0[r] * (qi * ci0) : -1e9f;
      const float a1 = v1 ? acc1[r] * (qi * ci1) : -1e9f;
      rm[r] = fmaxf(rm[r], fmaxf(a0, a1));
    }
  }

  // ---- reduce row-max across the 16 col-lanes; write per-half row-max
#pragma unroll
  for (int r = 0; r < 4; ++r) {
#pragma unroll
    for (int o = 1; o < 16; o <<= 1) rm[r] = fmaxf(rm[r], __shfl_xor(rm[r], o));
  }
  if (rA == 0) {
#pragma unroll
    for (int r = 0; r < 4; ++r)
      ws_rm[(size_t)bid * LQ + wave * 16 + hi * 4 + r] = rm[r];
  }
}

// ============================== K3: merge + MLP ==============================
__global__ __launch_bounds__(DIM)
void merge_mlp(const float* __restrict__ ws_rm, const float* __restrict__ pp,
               const float* __restrict__ nn, const int* __restrict__ qm,
               const float* __restrict__ W1, const float* __restrict__ b1,
               const float* __restrict__ W2, const float* __restrict__ b2,
               float* __restrict__ late, float* __restrict__ emb) {
  __shared__ float s_q[DIM], s_c[DIM], s_hq[DIM], s_hc[DIM];
  __shared__ float s_red[2][6], s_l[2];
  const int b = blockIdx.x;
  const int d = threadIdx.x;

  if (d < LQ) {
    const float m = fmaxf(ws_rm[(size_t)(2 * b) * LQ + d],
                          ws_rm[(size_t)(2 * b + 1) * LQ + d]);
    float ps = qm[b * LQ + d] ? m : 0.f;
#pragma unroll
    for (int o = 32; o; o >>= 1) ps += __shfl_xor(ps, o);
    if ((d & 63) == 0) s_l[d >> 6] = ps;
  }
  float sq = 0.f, sc = 0.f, nq = 0.f, nc = 0.f;
#pragma unroll
  for (int s = 0; s < 8; ++s) {
    sq += pp[(size_t)(b * 8 + s) * 768 + d];
    sc += pp[(size_t)(b * 8 + s) * 768 + DIM + d];
    nq += nn[(b * 8 + s) * 2];
    nc += nn[(b * 8 + s) * 2 + 1];
  }
  s_q[d] = sq / fmaxf(nq, 1e-9f);
  s_c[d] = sc / fmaxf(nc, 1e-9f);
  __syncthreads();

  float aq = b1[d], ac = b1[d];
#pragma unroll 8
  for (int k = 0; k < DIM; ++k) {
    const float w = W1[k * DIM + d];
    aq = fmaf(s_q[k], w, aq);
    ac = fmaf(s_c[k], w, ac);
  }
  s_hq[d] = fmaxf(aq, 0.f);
  s_hc[d] = fmaxf(ac, 0.f);
  __syncthreads();
  float pq = b2[d], pc = b2[d];
#pragma unroll 8
  for (int k = 0; k < DIM; ++k) {
    const float w = W2[k * DIM + d];
    pq = fmaf(s_hq[k], w, pq);
    pc = fmaf(s_hc[k], w, pc);
  }
  float q2 = pq * pq, c2 = pc * pc;
#pragma unroll
  for (int o = 32; o; o >>= 1) { q2 += __shfl_xor(q2, o); c2 += __shfl_xor(c2, o); }
  if ((d & 63) == 0) { s_red[0][d >> 6] = q2; s_red[1][d >> 6] = c2; }
  __syncthreads();
  float tq = 0.f, tc = 0.f;
#pragma unroll
  for (int w = 0; w < 6; ++w) { tq += s_red[0][w]; tc += s_red[1][w]; }
  emb[(size_t)b * DIM + d] = pq * (1.0f / fmaxf(sqrtf(tq), 1e-12f));
  emb[(size_t)(NB + b) * DIM + d] = pc * (1.0f / fmaxf(sqrtf(tc), 1e-12f));
  if (d == 0) late[b] = s_l[0] + s_l[1];
}

// ============================== K4: contrast =================================
__global__ __launch_bounds__(NB)
void contrast_kernel(const float* __restrict__ emb, float* __restrict__ out0) {
  __shared__ float s_q[DIM];
  const int i = blockIdx.x;
  for (int k = threadIdx.x; k < DIM; k += NB) s_q[k] = emb[(size_t)i * DIM + k];
  __syncthreads();
  const float* ce = emb + (size_t)(NB + threadIdx.x) * DIM;
  float acc = 0.f;
#pragma unroll 8
  for (int k = 0; k < DIM; ++k) acc = fmaf(s_q[k], ce[k], acc);
  out0[(size_t)i * NB + threadIdx.x] = acc / 0.07f;
}

// ===================== Fallback (round-1 proven path) ========================
#define TCD 32
#define QP 392
__device__ __forceinline__ unsigned short f2bf(float x) {
  union { float f; uint32_t u; } c; c.f = x;
  return (unsigned short)((c.u + 0x7fffu + ((c.u >> 16) & 1u)) >> 16);
}

__global__ __launch_bounds__(512, 1)
void fused_v1(const float* __restrict__ qtok, const float* __restrict__ ctok,
              const int* __restrict__ qm, const int* __restrict__ cm,
              float* __restrict__ pooled, float* __restrict__ late) {
  __shared__ unsigned short s_q[LQ][QP];
  __shared__ unsigned short s_c[TCD][QP];
  __shared__ float s_pq[8][DIM];
  __shared__ float s_pc[8][DIM];
  __shared__ float s_cnt[2][8];
  __shared__ int   s_cval[TCD];
  __shared__ float s_wsum[8];

  const int b = blockIdx.x;
  const int tid = threadIdx.x;
  const int wave = tid >> 6;
  const int lane = tid & 63;
  const int rA = lane & 15;
  const int kof = (lane >> 4) * 8;

  const float* qb = qtok + (size_t)b * LQ * DIM;
  const float* cb = ctok + (size_t)b * LC * DIM;
  const int* qmb = qm + b * LQ;
  const int* cmb = cm + b * LC;

  float pq[6] = {0.f,0.f,0.f,0.f,0.f,0.f};
  float cq = 0.f;
  for (int r0 = 0; r0 < 16; ++r0) {
    const int r = wave * 16 + r0;
    const float* src = qb + r * DIM;
    float v[6], ss = 0.f;
#pragma unroll
    for (int j = 0; j < 6; ++j) { v[j] = src[lane + 64 * j]; ss += v[j] * v[j]; }
#pragma unroll
    for (int o = 32; o; o >>= 1) ss += __shfl_xor(ss, o);
    const float inv = 1.0f / fmaxf(sqrtf(ss), 1e-12f);
    const float fm = (float)qmb[r];
#pragma unroll
    for (int j = 0; j < 6; ++j) {
      s_q[r][lane + 64 * j] = f2bf(v[j] * inv);
      pq[j] = fmaf(v[j], fm, pq[j]);
    }
    cq += fm;
  }
#pragma unroll
  for (int j = 0; j < 6; ++j) s_pq[wave][lane + 64 * j] = pq[j];
  if (lane == 0) s_cnt[0][wave] = cq;

  float rm[4] = {-1e9f, -1e9f, -1e9f, -1e9f};
  float pc[6] = {0.f,0.f,0.f,0.f,0.f,0.f};
  float cc = 0.f;

  for (int t = 0; t < LC / TCD; ++t) {
    __syncthreads();
#pragma unroll
    for (int r0 = 0; r0 < 4; ++r0) {
      const int r = wave * 4 + r0;
      const int crow = t * TCD + r;
      const float* src = cb + crow * DIM;
      float v[6], ss = 0.f;
#pragma unroll
      for (int j = 0; j < 6; ++j) { v[j] = src[lane + 64 * j]; ss += v[j] * v[j]; }
#pragma unroll
      for (int o = 32; o; o >>= 1) ss += __shfl_xor(ss, o);
      const float inv = 1.0f / fmaxf(sqrtf(ss), 1e-12f);
      const int mk = cmb[crow];
      const float fm = (float)mk;
#pragma unroll
      for (int j = 0; j < 6; ++j) {
        s_c[r][lane + 64 * j] = f2bf(v[j] * inv);
        pc[j] = fmaf(v[j], fm, pc[j]);
      }
      cc += fm;
      if (lane == 0) s_cval[r] = mk;
    }
    __syncthreads();

    const unsigned short* ap  = &s_q[wave * 16 + rA][kof];
    const unsigned short* bp0 = &s_c[rA][kof];
    const unsigned short* bp1 = &s_c[rA + 16][kof];
    f4 acc0 = {0.f,0.f,0.f,0.f};
    f4 acc1 = {0.f,0.f,0.f,0.f};
#pragma unroll
    for (int kk = 0; kk < 12; ++kk) {
      short8 a  = *(const short8*)(ap  + kk * 32);
      short8 b0 = *(const short8*)(bp0 + kk * 32);
      short8 b1 = *(const short8*)(bp1 + kk * 32);
      acc0 = __builtin_amdgcn_mfma_f32_16x16x32_bf16(a, b0, acc0, 0, 0, 0);
      acc1 = __builtin_amdgcn_mfma_f32_16x16x32_bf16(a, b1, acc1, 0, 0, 0);
    }
    const bool v0 = s_cval[rA] != 0;
    const bool v1 = s_cval[rA + 16] != 0;
#pragma unroll
    for (int r = 0; r < 4; ++r) {
      const float a0 = v0 ? acc0[r] : -1e9f;
      const float a1 = v1 ? acc1[r] : -1e9f;
      rm[r] = fmaxf(rm[r], fmaxf(a0, a1));
    }
  }

#pragma unroll
  for (int j = 0; j < 6; ++j) s_pc[wave][lane + 64 * j] = pc[j];
  if (lane == 0) s_cnt[1][wave] = cc;

#pragma unroll
  for (int r = 0; r < 4; ++r) {
#pragma unroll
    for (int o = 1; o < 16; o <<= 1) rm[r] = fmaxf(rm[r], __shfl_xor(rm[r], o));
  }
  float ps = 0.f;
  if (rA == 0) {
    const int rowb = wave * 16 + (lane >> 4) * 4;
#pragma unroll
    for (int r = 0; r < 4; ++r) ps += qmb[rowb + r] ? rm[r] : 0.f;
  }
#pragma unroll
  for (int o = 32; o; o >>= 1) ps += __shfl_xor(ps, o);
  if (lane == 0) s_wsum[wave] = ps;
  __syncthreads();

  if (tid < DIM) {
    float sq = 0.f, sc = 0.f, nq = 0.f, nc = 0.f;
#pragma unroll
    for (int w = 0; w < 8; ++w) {
      sq += s_pq[w][tid];
      sc += s_pc[w][tid];
      nq += s_cnt[0][w];
      nc += s_cnt[1][w];
    }
    pooled[b * DIM + tid] = sq / fmaxf(nq, 1e-9f);
    pooled[(NB + b) * DIM + tid] = sc / fmaxf(nc, 1e-9f);
  }
  if (tid == 0) {
    float tot = 0.f;
#pragma unroll
    for (int w = 0; w < 8; ++w) tot += s_wsum[w];
    late[b] = tot;
  }
}

__global__ __launch_bounds__(DIM)
void mlp_v1(const float* __restrict__ pooled,
            const float* __restrict__ W1, const float* __restrict__ b1,
            const float* __restrict__ W2, const float* __restrict__ b2,
            float* __restrict__ emb) {
  __shared__ float s_in[DIM];
  __shared__ float s_h[DIM];
  __shared__ float s_red[6];
  const int row = blockIdx.y * NB + blockIdx.x;
  const int d = threadIdx.x;
  s_in[d] = pooled[(size_t)row * DIM + d];
  __syncthreads();
  float acc = b1[d];
#pragma unroll 8
  for (int k = 0; k < DIM; ++k) acc = fmaf(s_in[k], W1[k * DIM + d], acc);
  s_h[d] = fmaxf(acc, 0.f);
  __syncthreads();
  float p = b2[d];
#pragma unroll 8
  for (int k = 0; k < DIM; ++k) p = fmaf(s_h[k], W2[k * DIM + d], p);
  float ss = p * p;
#pragma unroll
  for (int o = 32; o; o >>= 1) ss += __shfl_xor(ss, o);
  if ((d & 63) == 0) s_red[d >> 6] = ss;
  __syncthreads();
  float tot = 0.f;
#pragma unroll
  for (int w = 0; w < 6; ++w) tot += s_red[w];
  emb[(size_t)row * DIM + d] = p * (1.0f / fmaxf(sqrtf(tot), 1e-12f));
}

// ============================== launch =======================================
extern "C" void kernel_launch(void* const* d_in, const int* in_sizes, int n_in,
                              void* d_out, int out_size, void* d_ws, size_t ws_size,
                              hipStream_t stream) {
  const float* qtok = (const float*)d_in[0];
  const float* ctok = (const float*)d_in[1];
  const int*   qmm  = (const int*)d_in[2];
  const int*   cmm  = (const int*)d_in[3];
  const float* W1   = (const float*)d_in[4];
  const float* b1   = (const float*)d_in[5];
  const float* W2   = (const float*)d_in[6];
  const float* b2   = (const float*)d_in[7];

  float* out0 = (float*)d_out;   // [NB*NB]
  float* late = out0 + NB * NB;  // [NB]

  // main-path workspace layout
  const size_t PP_N   = (size_t)2048 * 768;
  const size_t NN_N   = 4096;
  const size_t RM_N   = (size_t)512 * LQ;
  const size_t EMB_N  = (size_t)2 * NB * DIM;
  const size_t QI_N   = (size_t)NB * LQ;
  const size_t CI_N   = (size_t)NB * LC;
  const size_t QN_N   = (size_t)NB * LQ * DIM;
  const size_t CN_N   = (size_t)NB * LC * DIM;
  const size_t NEED   = (PP_N + NN_N + RM_N + EMB_N + QI_N + CI_N) * 4
                      + (QN_N + CN_N) * 2;

  if (ws_size >= NEED) {
    float* pp  = (float*)d_ws;
    float* nn  = pp + PP_N;
    float* rm  = nn + NN_N;
    float* emb = rm + RM_N;
    float* qi  = emb + EMB_N;
    float* ci  = qi + QI_N;
    unsigned short* qn = (unsigned short*)(ci + CI_N);
    unsigned short* cn = qn + QN_N;

    hipLaunchKernelGGL(normalize_pool, dim3(2048), dim3(256), 0, stream,
                       qtok, ctok, qmm, cmm, qn, cn, qi, ci, pp, nn);
    hipLaunchKernelGGL(maxsim, dim3(512), dim3(512), 0, stream,
                       qn, cn, cmm, qi, ci, rm);
    hipLaunchKernelGGL(merge_mlp, dim3(NB), dim3(DIM), 0, stream,
                       rm, pp, nn, qmm, W1, b1, W2, b2, late, emb);
    hipLaunchKernelGGL(contrast_kernel, dim3(NB), dim3(NB), 0, stream, emb, out0);
  } else {
    float* pooled = (float*)d_ws;            // [2*NB][DIM]
    float* emb    = pooled + 2 * NB * DIM;   // [2*NB][DIM]
    hipLaunchKernelGGL(fused_v1, dim3(NB), dim3(512), 0, stream,
                       qtok, ctok, qmm, cmm, pooled, late);
    hipLaunchKernelGGL(mlp_v1, dim3(NB, 2), dim3(DIM), 0, stream,
                       pooled, W1, b1, W2, b2, emb);
    hipLaunchKernelGGL(contrast_kernel, dim3(NB), dim3(NB), 0, stream, emb, out0);
  }
}

// Round 9
// 108.491 us; speedup vs baseline: 1.7297x; 1.7297x over previous
//
#include <hip/hip_runtime.h>
#include <hip/hip_bf16.h>
#include <stdint.h>

#define NB 256
#define LQ 128
#define LC 512
#define DIM 384
#define CBP 392     // bf16 tile pitch in shorts (784 B)
#define NST 20      // 4 q tiles + 16 c tiles, 32 rows each

typedef __attribute__((ext_vector_type(8))) short short8;
typedef __attribute__((ext_vector_type(4))) float f4;
typedef __attribute__((ext_vector_type(2))) unsigned int u32x2;

__device__ __forceinline__ unsigned int pk2bf(float a, float b) {
  union { float f; uint32_t u; } x, y; x.f = a; y.f = b;
  uint32_t lo = (x.u + 0x7fffu + ((x.u >> 16) & 1u)) >> 16;
  uint32_t hi = (y.u + 0x7fffu + ((y.u >> 16) & 1u)) >> 16;
  return lo | (hi << 16);
}

// ============================ fused single-pass ==============================
// One block per batch, 8 waves. 20 stages of 32 rows. Register bank pair
// (v/h = 6 f4/lane each) holds tiles t and t+1; stage t consumes its bank
// (raw bf16 -> LDS, sumsq as side ILP, pooled partials in regs) then reissues
// the bank for t+2 -> 12 f4/lane outstanding continuously, vmcnt never 0
// mid-loop. One lgkm+barrier per stage (db parity makes the 2nd redundant).
// MFMA on raw bf16; cosine recovered at fold time via qi*ci (round-8 proven).
__global__ __launch_bounds__(512, 2)
void fused2(const float* __restrict__ qtok, const float* __restrict__ ctok,
            const int* __restrict__ qm, const int* __restrict__ cm,
            float* __restrict__ pooled, float* __restrict__ late) {
  __shared__ unsigned short s_cb[2][32][CBP];  // 50176 B (epilogue: f32 arena)
  __shared__ float s_qi[LQ];
  __shared__ float s_ci[2][32];
  __shared__ int s_qm[LQ];
  __shared__ int s_cm[LC];
  __shared__ float s_cnt[16];
  __shared__ float s_wsum[8];

  const int b = blockIdx.x, tid = threadIdx.x;
  const int wave = tid >> 6, lane = tid & 63;
  const int rA = lane & 15, hi = lane >> 4;
  const bool hiHalf = lane >= 32;
  const int l31 = lane & 31;

  const float* qb = qtok + (size_t)b * LQ * DIM;
  const float* cb = ctok + (size_t)b * LC * DIM;

  s_cm[tid] = cm[b * LC + tid];
  if (tid < LQ) s_qm[tid] = qm[b * LQ + tid];
  __syncthreads();  // masks visible; vmcnt drained before counted scheme

  f4 v0[4], h0[2], v1[4], h1[2];
  f4 pqA = {0,0,0,0}, pqB = {0,0,0,0}, pcA = {0,0,0,0}, pcB = {0,0,0,0};
  float cq = 0.f, cc = 0.f;
  float rm[4] = {-1e9f, -1e9f, -1e9f, -1e9f};
  short8 A[12] = {};

#define TBASE(t) (((t) < 4) ? (qb + (size_t)(t) * 32 * DIM) \
                            : (cb + (size_t)((t) - 4) * 32 * DIM))

#define ISSUE(V, H, base_) do {                                              \
    const float* bb_ = (base_);                                              \
    _Pragma("unroll")                                                        \
    for (int i_ = 0; i_ < 4; ++i_)                                           \
      V[i_] = *((const f4*)(bb_ + (size_t)(wave * 4 + i_) * DIM) + lane);    \
    _Pragma("unroll")                                                        \
    for (int j_ = 0; j_ < 2; ++j_)                                           \
      H[j_] = *((const f4*)(bb_ + (size_t)(wave * 4 + 2 * j_ +               \
                (hiHalf ? 1 : 0)) * DIM) + 64 + l31);                        \
  } while (0)

#define STAGE(T, V, H, BUF) do {                                             \
    const int t_ = (T);                                                      \
    if (t_ == NST - 1) { asm volatile("s_waitcnt vmcnt(0)" ::: "memory"); }  \
    else               { asm volatile("s_waitcnt vmcnt(6)" ::: "memory"); }  \
    __builtin_amdgcn_sched_barrier(0);                                       \
    const bool isq_ = t_ < 4;                                                \
    const int* mk_ = isq_ ? (s_qm + t_ * 32) : (s_cm + (t_ - 4) * 32);       \
    float ss_[4];                                                            \
    _Pragma("unroll")                                                        \
    for (int i_ = 0; i_ < 4; ++i_) {                                         \
      const int lr_ = wave * 4 + i_;                                         \
      u32x2 w_; w_[0] = pk2bf(V[i_].x, V[i_].y); w_[1] = pk2bf(V[i_].z, V[i_].w); \
      *(u32x2*)&s_cb[BUF][lr_][4 * lane] = w_;                               \
      ss_[i_] = V[i_].x * V[i_].x + V[i_].y * V[i_].y                        \
              + V[i_].z * V[i_].z + V[i_].w * V[i_].w;                       \
    }                                                                        \
    _Pragma("unroll")                                                        \
    for (int j_ = 0; j_ < 2; ++j_) {                                         \
      const int lr_ = wave * 4 + 2 * j_ + (hiHalf ? 1 : 0);                  \
      u32x2 w_; w_[0] = pk2bf(H[j_].x, H[j_].y); w_[1] = pk2bf(H[j_].z, H[j_].w); \
      *(u32x2*)&s_cb[BUF][lr_][256 + 4 * l31] = w_;                          \
      const float td_ = H[j_].x * H[j_].x + H[j_].y * H[j_].y               \
                      + H[j_].z * H[j_].z + H[j_].w * H[j_].w;              \
      if (hiHalf) ss_[2 * j_ + 1] += td_; else ss_[2 * j_] += td_;           \
    }                                                                        \
    _Pragma("unroll")                                                        \
    for (int o_ = 32; o_; o_ >>= 1) {                                        \
      _Pragma("unroll")                                                      \
      for (int i_ = 0; i_ < 4; ++i_) ss_[i_] += __shfl_xor(ss_[i_], o_);     \
    }                                                                        \
    float fm_[4];                                                            \
    _Pragma("unroll")                                                        \
    for (int i_ = 0; i_ < 4; ++i_) fm_[i_] = (float)mk_[wave * 4 + i_];      \
    if (isq_) {                                                              \
      _Pragma("unroll")                                                      \
      for (int i_ = 0; i_ < 4; ++i_) { pqA += V[i_] * fm_[i_]; cq += fm_[i_]; } \
      _Pragma("unroll")                                                      \
      for (int j_ = 0; j_ < 2; ++j_)                                         \
        pqB += H[j_] * (hiHalf ? fm_[2 * j_ + 1] : fm_[2 * j_]);             \
      if (lane == 0) {                                                       \
        _Pragma("unroll")                                                    \
        for (int i_ = 0; i_ < 4; ++i_)                                       \
          s_qi[t_ * 32 + wave * 4 + i_] = 1.0f / fmaxf(sqrtf(ss_[i_]), 1e-12f); \
      }                                                                      \
    } else {                                                                 \
      _Pragma("unroll")                                                      \
      for (int i_ = 0; i_ < 4; ++i_) { pcA += V[i_] * fm_[i_]; cc += fm_[i_]; } \
      _Pragma("unroll")                                                      \
      for (int j_ = 0; j_ < 2; ++j_)                                         \
        pcB += H[j_] * (hiHalf ? fm_[2 * j_ + 1] : fm_[2 * j_]);             \
      if (lane == 0) {                                                       \
        _Pragma("unroll")                                                    \
        for (int i_ = 0; i_ < 4; ++i_)                                       \
          s_ci[BUF][wave * 4 + i_] = 1.0f / fmaxf(sqrtf(ss_[i_]), 1e-12f);   \
      }                                                                      \
    }                                                                        \
    if (t_ + 2 < NST) { ISSUE(V, H, TBASE(t_ + 2)); }                        \
    asm volatile("s_waitcnt lgkmcnt(0)" ::: "memory");                       \
    __builtin_amdgcn_s_barrier();                                            \
    __builtin_amdgcn_sched_barrier(0);                                       \
    if (isq_) {                                                              \
      if ((wave >> 1) == t_) {                                               \
        const int lb_ = (wave & 1) * 16 + rA;                                \
        _Pragma("unroll")                                                    \
        for (int kk_ = 0; kk_ < 12; ++kk_)                                   \
          A[kk_] = *(const short8*)&s_cb[BUF][lb_][kk_ * 32 + hi * 8];       \
        asm volatile("s_waitcnt lgkmcnt(0)" ::: "memory");                   \
        __builtin_amdgcn_sched_barrier(0);                                   \
      }                                                                      \
    } else {                                                                 \
      f4 a0_ = {0,0,0,0}, a1_ = {0,0,0,0};                                   \
      _Pragma("unroll")                                                      \
      for (int kk_ = 0; kk_ < 12; ++kk_) {                                   \
        const short8 b0_ = *(const short8*)&s_cb[BUF][rA][kk_ * 32 + hi * 8];     \
        const short8 b1_ = *(const short8*)&s_cb[BUF][rA + 16][kk_ * 32 + hi * 8];\
        a0_ = __builtin_amdgcn_mfma_f32_16x16x32_bf16(A[kk_], b0_, a0_, 0, 0, 0); \
        a1_ = __builtin_amdgcn_mfma_f32_16x16x32_bf16(A[kk_], b1_, a1_, 0, 0, 0); \
      }                                                                      \
      const int tb_ = (t_ - 4) * 32;                                         \
      const bool m0_ = s_cm[tb_ + rA] != 0;                                  \
      const bool m1_ = s_cm[tb_ + rA + 16] != 0;                             \
      const float ci0_ = s_ci[BUF][rA], ci1_ = s_ci[BUF][rA + 16];           \
      _Pragma("unroll")                                                      \
      for (int r_ = 0; r_ < 4; ++r_) {                                       \
        const float qi_ = s_qi[wave * 16 + hi * 4 + r_];                     \
        const float x0_ = m0_ ? a0_[r_] * (qi_ * ci0_) : -1e9f;              \
        const float x1_ = m1_ ? a1_[r_] * (qi_ * ci1_) : -1e9f;              \
        rm[r_] = fmaxf(rm[r_], fmaxf(x0_, x1_));                             \
      }                                                                      \
    }                                                                        \
  } while (0)

  // prologue: banks for tiles 0 and 1 in flight
  ISSUE(v0, h0, TBASE(0));
  ISSUE(v1, h1, TBASE(1));

  for (int t = 0; t < NST; t += 2) {
    STAGE(t, v0, h0, 0);
    STAGE(t + 1, v1, h1, 1);
  }

  // ---------------- epilogue ----------------
  // row-max reduce across the 16 col-lanes; masked q sum
#pragma unroll
  for (int r = 0; r < 4; ++r) {
#pragma unroll
    for (int o = 1; o < 16; o <<= 1) rm[r] = fmaxf(rm[r], __shfl_xor(rm[r], o));
  }
  float ps = 0.f;
  if (rA == 0) {
    const int rowb = wave * 16 + hi * 4;
#pragma unroll
    for (int r = 0; r < 4; ++r) ps += s_qm[rowb + r] ? rm[r] : 0.f;
  }
#pragma unroll
  for (int o = 32; o; o >>= 1) ps += __shfl_xor(ps, o);
  if (lane == 0) s_wsum[wave] = ps;

  __syncthreads();  // stage-19 LDS reads done before arena reuse

  float* red = (float*)&s_cb[0][0][0];  // [8 waves][2 (q,c)][512] f32 = 32 KB
  *(f4*)&red[(wave * 2 + 0) * 512 + 4 * lane] = pqA;
  *(f4*)&red[(wave * 2 + 0) * 512 + 256 + (hiHalf ? 128 : 0) + 4 * l31] = pqB;
  *(f4*)&red[(wave * 2 + 1) * 512 + 4 * lane] = pcA;
  *(f4*)&red[(wave * 2 + 1) * 512 + 256 + (hiHalf ? 128 : 0) + 4 * l31] = pcB;
  if (lane == 0) { s_cnt[wave] = cq; s_cnt[8 + wave] = cc; }
  __syncthreads();

  if (tid < DIM) {
    float sq = 0.f, sc = 0.f, nq = 0.f, nc = 0.f;
    if (tid < 256) {
#pragma unroll
      for (int w = 0; w < 8; ++w) {
        sq += red[(w * 2 + 0) * 512 + tid];
        sc += red[(w * 2 + 1) * 512 + tid];
      }
    } else {
#pragma unroll
      for (int w = 0; w < 8; ++w) {
        sq += red[(w * 2 + 0) * 512 + tid] + red[(w * 2 + 0) * 512 + tid + 128];
        sc += red[(w * 2 + 1) * 512 + tid] + red[(w * 2 + 1) * 512 + tid + 128];
      }
    }
#pragma unroll
    for (int w = 0; w < 8; ++w) { nq += s_cnt[w]; nc += s_cnt[8 + w]; }
    pooled[b * DIM + tid] = sq / fmaxf(nq, 1e-9f);
    pooled[(NB + b) * DIM + tid] = sc / fmaxf(nc, 1e-9f);
  }
  if (tid == 0) {
    float tot = 0.f;
#pragma unroll
    for (int w = 0; w < 8; ++w) tot += s_wsum[w];
    late[b] = tot;
  }
}

// ================= tail kernels: round-1 proven shapes (~10 us) ==============
__global__ __launch_bounds__(DIM)
void mlp_v1(const float* __restrict__ pooled,
            const float* __restrict__ W1, const float* __restrict__ b1,
            const float* __restrict__ W2, const float* __restrict__ b2,
            float* __restrict__ emb) {
  __shared__ float s_in[DIM];
  __shared__ float s_h[DIM];
  __shared__ float s_red[6];
  const int row = blockIdx.y * NB + blockIdx.x;
  const int d = threadIdx.x;
  s_in[d] = pooled[(size_t)row * DIM + d];
  __syncthreads();
  float acc = b1[d];
#pragma unroll 8
  for (int k = 0; k < DIM; ++k) acc = fmaf(s_in[k], W1[k * DIM + d], acc);
  s_h[d] = fmaxf(acc, 0.f);
  __syncthreads();
  float p = b2[d];
#pragma unroll 8
  for (int k = 0; k < DIM; ++k) p = fmaf(s_h[k], W2[k * DIM + d], p);
  float ss = p * p;
#pragma unroll
  for (int o = 32; o; o >>= 1) ss += __shfl_xor(ss, o);
  if ((d & 63) == 0) s_red[d >> 6] = ss;
  __syncthreads();
  float tot = 0.f;
#pragma unroll
  for (int w = 0; w < 6; ++w) tot += s_red[w];
  emb[(size_t)row * DIM + d] = p * (1.0f / fmaxf(sqrtf(tot), 1e-12f));
}

__global__ __launch_bounds__(NB)
void contrast_kernel(const float* __restrict__ emb, float* __restrict__ out0) {
  __shared__ float s_q[DIM];
  const int i = blockIdx.x;
  for (int k = threadIdx.x; k < DIM; k += NB) s_q[k] = emb[(size_t)i * DIM + k];
  __syncthreads();
  const float* ce = emb + (size_t)(NB + threadIdx.x) * DIM;
  float acc = 0.f;
#pragma unroll 8
  for (int k = 0; k < DIM; ++k) acc = fmaf(s_q[k], ce[k], acc);
  out0[(size_t)i * NB + threadIdx.x] = acc / 0.07f;
}

// ============================== launch =======================================
extern "C" void kernel_launch(void* const* d_in, const int* in_sizes, int n_in,
                              void* d_out, int out_size, void* d_ws, size_t ws_size,
                              hipStream_t stream) {
  const float* qtok = (const float*)d_in[0];
  const float* ctok = (const float*)d_in[1];
  const int*   qmm  = (const int*)d_in[2];
  const int*   cmm  = (const int*)d_in[3];
  const float* W1   = (const float*)d_in[4];
  const float* b1   = (const float*)d_in[5];
  const float* W2   = (const float*)d_in[6];
  const float* b2   = (const float*)d_in[7];

  float* out0 = (float*)d_out;            // [NB*NB]
  float* late = out0 + NB * NB;           // [NB]
  float* pooled = (float*)d_ws;           // [2*NB][DIM]
  float* emb    = pooled + 2 * NB * DIM;  // [2*NB][DIM]

  hipLaunchKernelGGL(fused2, dim3(NB), dim3(512), 0, stream,
                     qtok, ctok, qmm, cmm, pooled, late);
  hipLaunchKernelGGL(mlp_v1, dim3(NB, 2), dim3(DIM), 0, stream,
                     pooled, W1, b1, W2, b2, emb);
  hipLaunchKernelGGL(contrast_kernel, dim3(NB), dim3(NB), 0, stream, emb, out0);
}